// Round 8
// baseline (530.381 us; speedup 1.0000x reference)
//
#include <hip/hip_runtime.h>
#include <hip/hip_bf16.h>

typedef _Float16 f16x8 __attribute__((ext_vector_type(8)));
typedef unsigned short u16x8 __attribute__((ext_vector_type(8)));
typedef unsigned short u16x4 __attribute__((ext_vector_type(4)));
typedef float f32x4 __attribute__((ext_vector_type(4)));

static constexpr int Bn = 2;
static constexpr int Tn = 2048;
static constexpr int En = 1024;
static constexpr int Hn = 16;
static constexpr int Dn = 64;
#define LOG2E 1.44269504088896340736f

static constexpr int TS = 136;  // qkv epilogue transpose stride
static constexpr int PS = 136;  // attn P row stride (shorts); b64/b128 ops land
                                // at the 32-bank phase floor (verified: 4cyc/op)

__device__ __forceinline__ unsigned short f2h(float x) {
  _Float16 h = (_Float16)x;
  return __builtin_bit_cast(unsigned short, h);
}
__device__ __forceinline__ float h2f(unsigned short u) {
  return (float)__builtin_bit_cast(_Float16, u);
}
__device__ __forceinline__ f16x8 ldh8(const unsigned short* p) {
  return __builtin_bit_cast(f16x8, *reinterpret_cast<const u16x8*>(p));
}
__device__ __forceinline__ unsigned int pk2(float a, float b) {
  return __builtin_bit_cast(unsigned int, __builtin_amdgcn_cvt_pkrtz(a, b));
}
// async global->LDS, 16B/lane; LDS dest must be wave-uniform base (+lane*16)
__device__ __forceinline__ void gld16(const void* g, void* l) {
  __builtin_amdgcn_global_load_lds(
      (__attribute__((address_space(1))) void*)(const_cast<void*>(g)),
      (__attribute__((address_space(3))) void*)(l), 16, 0, 0);
}

// fp16 hi/lo split: (hi + lo) == x to ~22 mantissa bits
__global__ __launch_bounds__(256) void split_f32_f16(
    const float* __restrict__ src, unsigned short* __restrict__ hi,
    unsigned short* __restrict__ lo)
{
  const int i = (blockIdx.x * 256 + threadIdx.x) * 4;
  const float4 v = *reinterpret_cast<const float4*>(src + i);
  ushort4 h, l;
  h.x = f2h(v.x); l.x = f2h(v.x - h2f(h.x));
  h.y = f2h(v.y); l.y = f2h(v.y - h2f(h.y));
  h.z = f2h(v.z); l.z = f2h(v.z - h2f(h.z));
  h.w = f2h(v.w); l.w = f2h(v.w - h2f(h.w));
  *reinterpret_cast<ushort4*>(hi + i) = h;
  *reinterpret_cast<ushort4*>(lo + i) = l;
}

__global__ __launch_bounds__(256) void cvt_f32_f16(
    const float* __restrict__ src, unsigned short* __restrict__ dst)
{
  const int i = (blockIdx.x * 256 + threadIdx.x) * 4;
  const float4 v = *reinterpret_cast<const float4*>(src + i);
  ushort4 u;
  u.x = f2h(v.x); u.y = f2h(v.y); u.z = f2h(v.z); u.w = f2h(v.w);
  *reinterpret_cast<ushort4*>(dst + i) = u;
}

// QKV GEMM, fp16: A = x as fp16 hi+lo (exact), B = w_qkv fp16. Q/K: 2 MFMA,
// V: 1 MFMA. Permuted column tiling c' = kk*1024 + hh*64 + dd
// (w_qkv row n = dd*48+kk*16+hh). Outputs fp16: Q(x8*log2e),K [b,h,t,d]; V [b,h,d,t].
__global__ __launch_bounds__(256) void gemm_qkv(
    const unsigned short* __restrict__ xh, const unsigned short* __restrict__ xl,
    const unsigned short* __restrict__ wf,
    unsigned short* __restrict__ Qf, unsigned short* __restrict__ Kf,
    unsigned short* __restrict__ Vf, int M, int K)
{
  __shared__ unsigned short smem[128 * TS];  // 34816 B; reused by epilogue
  unsigned short* shAh = smem;               // 128x32 each, unpadded
  unsigned short* shAl = smem + 4096;
  unsigned short* shB = smem + 8192;

  const int tid = threadIdx.x;
  const int w = tid >> 6, L = tid & 63, qd = L >> 4, lr = L & 15;
  const int m0 = blockIdx.y * 128;
  const int kk = blockIdx.x >> 3;          // 0=Q 1=K 2=V (uniform per block)
  const int hh0 = (blockIdx.x & 7) * 2;    // two heads per block
  const int wm = (w >> 1) * 64, wn = (w & 1) * 64;

  f32x4 acc[4][4] = {};

  for (int k0 = 0; k0 < K; k0 += 32) {
#pragma unroll
    for (int p = 0; p < 2; ++p) {
      const int c = p * 256 + tid;
      const int row = c >> 2, slot = c & 3;
      const int dd = row & 63, hl = row >> 6;
      const int nB = dd * 48 + kk * 16 + hh0 + hl;
      const size_t aoff = (size_t)(m0 + row) * K + k0 + slot * 8;
      const size_t boff = (size_t)nB * K + k0 + slot * 8;
      const int base = (p * 4 + w) * 512;  // wave-uniform LDS base (shorts)
      gld16(xh + aoff, &shAh[base]);
      gld16(wf + boff, &shB[base]);
      if (kk < 2) gld16(xl + aoff, &shAl[base]);
    }
    __syncthreads();

    f16x8 afh[4], bf[4];
#pragma unroll
    for (int mt = 0; mt < 4; ++mt)
      afh[mt] = ldh8(&shAh[(wm + mt * 16 + lr) * 32 + qd * 8]);
#pragma unroll
    for (int nt = 0; nt < 4; ++nt)
      bf[nt] = ldh8(&shB[(wn + nt * 16 + lr) * 32 + qd * 8]);
    if (kk < 2) {
      f16x8 afl[4];
#pragma unroll
      for (int mt = 0; mt < 4; ++mt)
        afl[mt] = ldh8(&shAl[(wm + mt * 16 + lr) * 32 + qd * 8]);
#pragma unroll
      for (int mt = 0; mt < 4; ++mt)
#pragma unroll
        for (int nt = 0; nt < 4; ++nt) {
          acc[mt][nt] = __builtin_amdgcn_mfma_f32_16x16x32_f16(afh[mt], bf[nt], acc[mt][nt], 0, 0, 0);
          acc[mt][nt] = __builtin_amdgcn_mfma_f32_16x16x32_f16(afl[mt], bf[nt], acc[mt][nt], 0, 0, 0);
        }
    } else {
#pragma unroll
      for (int mt = 0; mt < 4; ++mt)
#pragma unroll
        for (int nt = 0; nt < 4; ++nt)
          acc[mt][nt] = __builtin_amdgcn_mfma_f32_16x16x32_f16(afh[mt], bf[nt], acc[mt][nt], 0, 0, 0);
    }
    __syncthreads();
  }

  // epilogue: fp16 into LDS transpose buffer -> coalesced 16B stores
  const int b = m0 >> 11;
  const int t0 = m0 & (Tn - 1);
  // fold *sqrt(d)*log2(e) into Q so attn softmax is exp2(s - m) directly
  const float qscale = (kk == 0) ? 8.0f * LOG2E : 1.0f;
#pragma unroll
  for (int mt = 0; mt < 4; ++mt)
#pragma unroll
    for (int nt = 0; nt < 4; ++nt)
#pragma unroll
      for (int r = 0; r < 4; ++r) {
        const int ml = wm + mt * 16 + qd * 4 + r;  // C/D row=(lane>>4)*4+reg
        const int cl = wn + nt * 16 + lr;          // C/D col=lane&15
        smem[ml * TS + cl] = f2h(acc[mt][nt][r] * qscale);
      }
  __syncthreads();

  unsigned short* dst = (kk == 0) ? Qf : (kk == 1) ? Kf : Vf;
  if (kk < 2) {
#pragma unroll
    for (int p = 0; p < 8; ++p) {
      const int s = p * 256 + tid;
      const int tl = s >> 4, sub = s & 15;
      const int hl = sub >> 3, oct = sub & 7;
      const u16x8 v = *reinterpret_cast<const u16x8*>(&smem[tl * TS + hl * 64 + oct * 8]);
      *reinterpret_cast<u16x8*>(
          dst + ((size_t)(b * Hn + hh0 + hl) * Tn + t0 + tl) * Dn + oct * 8) = v;
    }
  } else {
#pragma unroll
    for (int p = 0; p < 8; ++p) {
      const int s = p * 256 + tid;
      const int cl = s >> 4, oct = s & 15;
      const int hl = cl >> 6, dd = cl & 63;
      u16x8 v;
#pragma unroll
      for (int j = 0; j < 8; ++j) v[j] = smem[(oct * 8 + j) * TS + cl];
      *reinterpret_cast<u16x8*>(
          dst + ((size_t)((b * Hn + hh0 + hl) * Dn + dd)) * Tn + t0 + oct * 8) = v;
    }
  }
}

// Flash attention, fp16, swapped-operand QK^T (S^T in registers: lane holds one
// q-row = lane&15), K/V direct global->reg (L2/L1-resident, no LDS staging, NO
// barriers). 16 q-rows per wave, 64-row blocks, grid 1024 -> 4 blocks/CU =
// 16 waves/CU (was grid-limited at 8). All 4 waves of a block stream the same
// K/V tile -> L1 reuse. P transposed via packed b64 LDS round-trip (per-wave
// buffer, phase-floor banking). Output O^T, packed 8B stores.
// Qf(x8*log2e),Kf: [b,h,t,d]  Vf: [b,h,d,t]  AO: fp16.
__global__ __launch_bounds__(256, 4) void attn_kernel(
    const unsigned short* __restrict__ Qf, const unsigned short* __restrict__ Kf,
    const unsigned short* __restrict__ Vf, unsigned short* __restrict__ AOf)
{
  __shared__ unsigned short shP[4 * 16 * PS];  // per-wave 16x128, 17408 B
  const int tid = threadIdx.x;
  const int w = tid >> 6, L = tid & 63, qd = L >> 4, lr = L & 15;
  const int q0 = blockIdx.x * 64;
  const int bh = blockIdx.y;
  unsigned short* myP = &shP[w * 16 * PS];

  f16x8 aq[2];
  {
    const size_t qoff = ((size_t)bh * Tn + q0 + w * 16 + lr) * Dn;
    aq[0] = ldh8(Qf + qoff + qd * 8);
    aq[1] = ldh8(Qf + qoff + 32 + qd * 8);
  }
  f16x8 ones;
#pragma unroll
  for (int j = 0; j < 8; ++j) ones[j] = (_Float16)1.0f;

  // per-lane global bases (16B-aligned, coalesced in 64B row segments)
  const unsigned short* Kbase = Kf + ((size_t)bh * Tn + lr) * Dn + qd * 8;
  const unsigned short* Vbase = Vf + ((size_t)bh * Dn + lr) * Tn + qd * 8;

  f32x4 oacc[4] = {};
  float mrow = -1e30f, lsum = 0.f;

  // prologue: prefetch K tile 0 (16 x b128 = full 128x64 tile per wave)
  f16x8 kreg[8][2];
#pragma unroll
  for (int ct = 0; ct < 8; ++ct)
#pragma unroll
    for (int kc = 0; kc < 2; ++kc)
      kreg[ct][kc] = ldh8(Kbase + (size_t)(ct * 16) * Dn + kc * 32);

  for (int j0 = 0; j0 < Tn; j0 += 128) {
    // issue V loads early: vreg[kcv][nt] = V^T[d=nt*16+lr][j0+kcv*32+qd*8..]
    f16x8 vreg[4][4];
#pragma unroll
    for (int kcv = 0; kcv < 4; ++kcv)
#pragma unroll
      for (int nt = 0; nt < 4; ++nt)
        vreg[kcv][nt] = ldh8(Vbase + (size_t)(nt * 16) * Tn + j0 + kcv * 32);

    // S^T = mfma(K, Q): lane holds S'[q=lr][k = ct*16 + qd*4 + r]
    f32x4 s2[8];
#pragma unroll
    for (int ct = 0; ct < 8; ++ct) {
      s2[ct] = f32x4{0.f, 0.f, 0.f, 0.f};
#pragma unroll
      for (int kc = 0; kc < 2; ++kc)
        s2[ct] = __builtin_amdgcn_mfma_f32_16x16x32_f16(kreg[ct][kc], aq[kc], s2[ct], 0, 0, 0);
    }

    // row-local softmax (log2 domain; Q pre-scaled by 8*log2e)
    float tm = s2[0][0];
#pragma unroll
    for (int ct = 0; ct < 8; ++ct)
#pragma unroll
      for (int r = 0; r < 4; ++r) tm = fmaxf(tm, s2[ct][r]);
    tm = fmaxf(tm, __shfl_xor(tm, 16, 64));
    tm = fmaxf(tm, __shfl_xor(tm, 32, 64));
    const float mn = fmaxf(mrow, tm);
    const float alpha = exp2f(mrow - mn);
    mrow = mn;
#pragma unroll
    for (int ct = 0; ct < 8; ++ct)
#pragma unroll
      for (int r = 0; r < 4; ++r)
        s2[ct][r] = exp2f(s2[ct][r] - mrow);  // arg <= 0
#pragma unroll
    for (int nt = 0; nt < 4; ++nt)
#pragma unroll
      for (int r = 0; r < 4; ++r) oacc[nt][r] *= alpha;

    // pack P^T rows: lane owns 4 consecutive k -> b64 write (phase-floor banks)
#pragma unroll
    for (int ct = 0; ct < 8; ++ct) {
      uint2 d2;
      d2.x = pk2(s2[ct][0], s2[ct][1]);
      d2.y = pk2(s2[ct][2], s2[ct][3]);
      *reinterpret_cast<uint2*>(&myP[lr * PS + ct * 16 + qd * 4]) = d2;
    }

    // prefetch next K tile while PV runs
    if (j0 + 128 < Tn) {
#pragma unroll
      for (int ct = 0; ct < 8; ++ct)
#pragma unroll
        for (int kc = 0; kc < 2; ++kc)
          kreg[ct][kc] = ldh8(Kbase + (size_t)(j0 + 128 + ct * 16) * Dn + kc * 32);
    }

    // PV: O^T += mfma(V, P); rowsum via ones-MFMA (lane scalar at col q=lr)
    f32x4 sacc = {};
#pragma unroll
    for (int kcv = 0; kcv < 4; ++kcv) {
      const f16x8 pa = ldh8(&myP[lr * PS + kcv * 32 + qd * 8]);
#pragma unroll
      for (int nt = 0; nt < 4; ++nt)
        oacc[nt] = __builtin_amdgcn_mfma_f32_16x16x32_f16(vreg[kcv][nt], pa, oacc[nt], 0, 0, 0);
      sacc = __builtin_amdgcn_mfma_f32_16x16x32_f16(ones, pa, sacc, 0, 0, 0);
    }
    lsum = lsum * alpha + sacc[0];
  }

  // epilogue: O^T normalized by per-lane lsum, packed 8B stores
  const int b = bh >> 4, h = bh & 15;
  const float inv = 1.0f / lsum;
  const int q = q0 + w * 16 + lr;
#pragma unroll
  for (int nt = 0; nt < 4; ++nt) {
    unsigned short o[4];
#pragma unroll
    for (int r = 0; r < 4; ++r) o[r] = f2h(oacc[nt][r] * inv);
    const int col = h * 64 + nt * 16 + qd * 4;
    *reinterpret_cast<u16x4*>(&AOf[((size_t)b * Tn + q) * En + col]) =
        u16x4{o[0], o[1], o[2], o[3]};
  }
}

// Out-projection: OUT f32; A = AO fp16, B = wout fp16 (pre-cast).
__global__ __launch_bounds__(256) void gemm_out(
    const unsigned short* __restrict__ A, const unsigned short* __restrict__ Bm,
    float* __restrict__ C, int M, int N, int K)
{
  __shared__ unsigned short shA[128 * 32];
  __shared__ unsigned short shB[128 * 32];
  const int tid = threadIdx.x;
  const int w = tid >> 6, L = tid & 63, qd = L >> 4, lr = L & 15;
  const int m0 = blockIdx.y * 128;
  const int n0 = blockIdx.x * 128;
  const int wm = (w >> 1) * 64, wn = (w & 1) * 64;

  f32x4 acc[4][4] = {};

  for (int k0 = 0; k0 < K; k0 += 32) {
#pragma unroll
    for (int p = 0; p < 2; ++p) {
      const int c = p * 256 + tid;
      const int row = c >> 2, slot = c & 3;
      const int base = (p * 4 + w) * 512;
      gld16(A + (size_t)(m0 + row) * K + k0 + slot * 8, &shA[base]);
      gld16(Bm + (size_t)(n0 + row) * K + k0 + slot * 8, &shB[base]);
    }
    __syncthreads();

    f16x8 af[4], bf[4];
#pragma unroll
    for (int mt = 0; mt < 4; ++mt)
      af[mt] = ldh8(&shA[(wm + mt * 16 + lr) * 32 + qd * 8]);
#pragma unroll
    for (int nt = 0; nt < 4; ++nt)
      bf[nt] = ldh8(&shB[(wn + nt * 16 + lr) * 32 + qd * 8]);
#pragma unroll
    for (int mt = 0; mt < 4; ++mt)
#pragma unroll
      for (int nt = 0; nt < 4; ++nt)
        acc[mt][nt] = __builtin_amdgcn_mfma_f32_16x16x32_f16(af[mt], bf[nt], acc[mt][nt], 0, 0, 0);
    __syncthreads();
  }

#pragma unroll
  for (int mt = 0; mt < 4; ++mt)
#pragma unroll
    for (int nt = 0; nt < 4; ++nt)
#pragma unroll
      for (int r = 0; r < 4; ++r) {
        const int m = m0 + wm + mt * 16 + qd * 4 + r;
        const int n = n0 + wn + nt * 16 + lr;
        C[(size_t)m * N + n] = acc[mt][nt][r];
      }
}

extern "C" void kernel_launch(void* const* d_in, const int* in_sizes, int n_in,
                              void* d_out, int out_size, void* d_ws, size_t ws_size,
                              hipStream_t stream) {
  (void)in_sizes; (void)n_in; (void)out_size; (void)ws_size;
  const float* x = (const float*)d_in[0];      // [2,2048,1024] f32
  const float* wqkv = (const float*)d_in[1];   // [3072,1024]  f32
  const float* wout = (const float*)d_in[2];   // [1024,1024]  f32
  float* out = (float*)d_out;                  // [2,2048,1024] f32

  const size_t elems = (size_t)Bn * Hn * Tn * Dn;  // 4M elems (8 MiB fp16)
  unsigned short* Qf = (unsigned short*)d_ws;
  unsigned short* Kf = Qf + elems;
  unsigned short* Vf = Kf + elems;
  unsigned short* AOf = Vf + elems;
  unsigned short* wf = AOf + elems;                // fp16 w_qkv, 3M
  unsigned short* wof = wf + (size_t)3 * En * En;  // fp16 wout, 1M (40 MiB)

  // d_out (16 MiB) doubles as scratch for x hi/lo; overwritten by gemm_out.
  unsigned short* xh = (unsigned short*)d_out;
  unsigned short* xl = xh + elems;

  const int M = Bn * Tn;  // 4096
  dim3 blk(256);
  split_f32_f16<<<dim3((int)(elems / 1024)), blk, 0, stream>>>(x, xh, xl);
  cvt_f32_f16<<<dim3(3 * En * En / 1024), blk, 0, stream>>>(wqkv, wf);
  cvt_f32_f16<<<dim3(En * En / 1024), blk, 0, stream>>>(wout, wof);
  gemm_qkv<<<dim3(24, M / 128), blk, 0, stream>>>(
      xh, xl, wf, Qf, Kf, Vf, M, En);
  attn_kernel<<<dim3(Tn / 64, Bn * Hn), blk, 0, stream>>>(Qf, Kf, Vf, AOf);
  gemm_out<<<dim3(En / 128, M / 128), blk, 0, stream>>>(
      AOf, wof, out, M, En, En);
}

// Round 10
// 411.128 us; speedup vs baseline: 1.2901x; 1.2901x over previous
//
#include <hip/hip_runtime.h>
#include <hip/hip_bf16.h>

typedef _Float16 f16x8 __attribute__((ext_vector_type(8)));
typedef unsigned short u16x8 __attribute__((ext_vector_type(8)));
typedef unsigned short u16x4 __attribute__((ext_vector_type(4)));
typedef float f32x4 __attribute__((ext_vector_type(4)));

static constexpr int Bn = 2;
static constexpr int Tn = 2048;
static constexpr int En = 1024;
static constexpr int Hn = 16;
static constexpr int Dn = 64;
#define LOG2E 1.44269504088896340736f

static constexpr int TS = 136;  // qkv epilogue transpose stride
static constexpr int PS = 136;  // attn P row stride (shorts); b64/b128 ops land
                                // at the 32-bank phase floor (verified: 4cyc/op)

__device__ __forceinline__ unsigned short f2h(float x) {
  _Float16 h = (_Float16)x;
  return __builtin_bit_cast(unsigned short, h);
}
__device__ __forceinline__ float h2f(unsigned short u) {
  return (float)__builtin_bit_cast(_Float16, u);
}
__device__ __forceinline__ f16x8 ldh8(const unsigned short* p) {
  return __builtin_bit_cast(f16x8, *reinterpret_cast<const u16x8*>(p));
}
__device__ __forceinline__ unsigned int pk2(float a, float b) {
  return __builtin_bit_cast(unsigned int, __builtin_amdgcn_cvt_pkrtz(a, b));
}
// async global->LDS, 16B/lane; LDS dest must be wave-uniform base (+lane*16)
__device__ __forceinline__ void gld16(const void* g, void* l) {
  __builtin_amdgcn_global_load_lds(
      (__attribute__((address_space(1))) void*)(const_cast<void*>(g)),
      (__attribute__((address_space(3))) void*)(l), 16, 0, 0);
}

// fp16 hi/lo split: (hi + lo) == x to ~22 mantissa bits
__global__ __launch_bounds__(256) void split_f32_f16(
    const float* __restrict__ src, unsigned short* __restrict__ hi,
    unsigned short* __restrict__ lo)
{
  const int i = (blockIdx.x * 256 + threadIdx.x) * 4;
  const float4 v = *reinterpret_cast<const float4*>(src + i);
  ushort4 h, l;
  h.x = f2h(v.x); l.x = f2h(v.x - h2f(h.x));
  h.y = f2h(v.y); l.y = f2h(v.y - h2f(h.y));
  h.z = f2h(v.z); l.z = f2h(v.z - h2f(h.z));
  h.w = f2h(v.w); l.w = f2h(v.w - h2f(h.w));
  *reinterpret_cast<ushort4*>(hi + i) = h;
  *reinterpret_cast<ushort4*>(lo + i) = l;
}

__global__ __launch_bounds__(256) void cvt_f32_f16(
    const float* __restrict__ src, unsigned short* __restrict__ dst)
{
  const int i = (blockIdx.x * 256 + threadIdx.x) * 4;
  const float4 v = *reinterpret_cast<const float4*>(src + i);
  ushort4 u;
  u.x = f2h(v.x); u.y = f2h(v.y); u.z = f2h(v.z); u.w = f2h(v.w);
  *reinterpret_cast<ushort4*>(dst + i) = u;
}

// QKV GEMM, fp16: A = x as fp16 hi+lo (exact), B = w_qkv fp16. Q/K: 2 MFMA,
// V: 1 MFMA. Permuted column tiling c' = kk*1024 + hh*64 + dd
// (w_qkv row n = dd*48+kk*16+hh). Outputs fp16: Q(x8*log2e),K [b,h,t,d]; V [b,h,d,t].
__global__ __launch_bounds__(256) void gemm_qkv(
    const unsigned short* __restrict__ xh, const unsigned short* __restrict__ xl,
    const unsigned short* __restrict__ wf,
    unsigned short* __restrict__ Qf, unsigned short* __restrict__ Kf,
    unsigned short* __restrict__ Vf, int M, int K)
{
  __shared__ unsigned short smem[128 * TS];  // 34816 B; reused by epilogue
  unsigned short* shAh = smem;               // 128x32 each, unpadded
  unsigned short* shAl = smem + 4096;
  unsigned short* shB = smem + 8192;

  const int tid = threadIdx.x;
  const int w = tid >> 6, L = tid & 63, qd = L >> 4, lr = L & 15;
  const int m0 = blockIdx.y * 128;
  const int kk = blockIdx.x >> 3;          // 0=Q 1=K 2=V (uniform per block)
  const int hh0 = (blockIdx.x & 7) * 2;    // two heads per block
  const int wm = (w >> 1) * 64, wn = (w & 1) * 64;

  f32x4 acc[4][4] = {};

  for (int k0 = 0; k0 < K; k0 += 32) {
#pragma unroll
    for (int p = 0; p < 2; ++p) {
      const int c = p * 256 + tid;
      const int row = c >> 2, slot = c & 3;
      const int dd = row & 63, hl = row >> 6;
      const int nB = dd * 48 + kk * 16 + hh0 + hl;
      const size_t aoff = (size_t)(m0 + row) * K + k0 + slot * 8;
      const size_t boff = (size_t)nB * K + k0 + slot * 8;
      const int base = (p * 4 + w) * 512;  // wave-uniform LDS base (shorts)
      gld16(xh + aoff, &shAh[base]);
      gld16(wf + boff, &shB[base]);
      if (kk < 2) gld16(xl + aoff, &shAl[base]);
    }
    __syncthreads();

    f16x8 afh[4], bf[4];
#pragma unroll
    for (int mt = 0; mt < 4; ++mt)
      afh[mt] = ldh8(&shAh[(wm + mt * 16 + lr) * 32 + qd * 8]);
#pragma unroll
    for (int nt = 0; nt < 4; ++nt)
      bf[nt] = ldh8(&shB[(wn + nt * 16 + lr) * 32 + qd * 8]);
    if (kk < 2) {
      f16x8 afl[4];
#pragma unroll
      for (int mt = 0; mt < 4; ++mt)
        afl[mt] = ldh8(&shAl[(wm + mt * 16 + lr) * 32 + qd * 8]);
#pragma unroll
      for (int mt = 0; mt < 4; ++mt)
#pragma unroll
        for (int nt = 0; nt < 4; ++nt) {
          acc[mt][nt] = __builtin_amdgcn_mfma_f32_16x16x32_f16(afh[mt], bf[nt], acc[mt][nt], 0, 0, 0);
          acc[mt][nt] = __builtin_amdgcn_mfma_f32_16x16x32_f16(afl[mt], bf[nt], acc[mt][nt], 0, 0, 0);
        }
    } else {
#pragma unroll
      for (int mt = 0; mt < 4; ++mt)
#pragma unroll
        for (int nt = 0; nt < 4; ++nt)
          acc[mt][nt] = __builtin_amdgcn_mfma_f32_16x16x32_f16(afh[mt], bf[nt], acc[mt][nt], 0, 0, 0);
    }
    __syncthreads();
  }

  // epilogue: fp16 into LDS transpose buffer -> coalesced 16B stores
  const int b = m0 >> 11;
  const int t0 = m0 & (Tn - 1);
  // fold *sqrt(d)*log2(e) into Q so attn softmax is exp2(s - m) directly
  const float qscale = (kk == 0) ? 8.0f * LOG2E : 1.0f;
#pragma unroll
  for (int mt = 0; mt < 4; ++mt)
#pragma unroll
    for (int nt = 0; nt < 4; ++nt)
#pragma unroll
      for (int r = 0; r < 4; ++r) {
        const int ml = wm + mt * 16 + qd * 4 + r;  // C/D row=(lane>>4)*4+reg
        const int cl = wn + nt * 16 + lr;          // C/D col=lane&15
        smem[ml * TS + cl] = f2h(acc[mt][nt][r] * qscale);
      }
  __syncthreads();

  unsigned short* dst = (kk == 0) ? Qf : (kk == 1) ? Kf : Vf;
  if (kk < 2) {
#pragma unroll
    for (int p = 0; p < 8; ++p) {
      const int s = p * 256 + tid;
      const int tl = s >> 4, sub = s & 15;
      const int hl = sub >> 3, oct = sub & 7;
      const u16x8 v = *reinterpret_cast<const u16x8*>(&smem[tl * TS + hl * 64 + oct * 8]);
      *reinterpret_cast<u16x8*>(
          dst + ((size_t)(b * Hn + hh0 + hl) * Tn + t0 + tl) * Dn + oct * 8) = v;
    }
  } else {
#pragma unroll
    for (int p = 0; p < 8; ++p) {
      const int s = p * 256 + tid;
      const int cl = s >> 4, oct = s & 15;
      const int hl = cl >> 6, dd = cl & 63;
      u16x8 v;
#pragma unroll
      for (int j = 0; j < 8; ++j) v[j] = smem[(oct * 8 + j) * TS + cl];
      *reinterpret_cast<u16x8*>(
          dst + ((size_t)((b * Hn + hh0 + hl) * Dn + dd)) * Tn + t0 + oct * 8) = v;
    }
  }
}

// Flash attention, fp16, swapped-operand QK^T (S^T in registers: lane holds one
// q-row = lane&15), K/V direct global->reg (L2/L3-resident, no LDS staging, NO
// barriers). 16 q-rows per wave, 64-row blocks, grid 1024 -> 4 blocks/CU IF
// VGPR <= 128. launch_bounds(256,2): (256,4) forced a 64-VGPR allocation with
// catastrophic scratch spill (728 MB writes, round 8); (256,2) compiled the
// same structure spill-free at 112 VGPR (round 5). Loads are placed at their
// use sites (K per-ct, V per-kcv) so the allocator needn't hold whole-tile
// arrays; 16 waves/CU TLP hides the latency instead. P transposed via packed
// b64 LDS round-trip (per-wave buffer, phase-floor banking). Output O^T.
// Qf(x8*log2e),Kf: [b,h,t,d]  Vf: [b,h,d,t]  AO: fp16.
__global__ __launch_bounds__(256, 2) void attn_kernel(
    const unsigned short* __restrict__ Qf, const unsigned short* __restrict__ Kf,
    const unsigned short* __restrict__ Vf, unsigned short* __restrict__ AOf)
{
  __shared__ unsigned short shP[4 * 16 * PS];  // per-wave 16x128, 17408 B
  const int tid = threadIdx.x;
  const int w = tid >> 6, L = tid & 63, qd = L >> 4, lr = L & 15;
  const int q0 = blockIdx.x * 64;
  const int bh = blockIdx.y;
  unsigned short* myP = &shP[w * 16 * PS];

  f16x8 aq[2];
  {
    const size_t qoff = ((size_t)bh * Tn + q0 + w * 16 + lr) * Dn;
    aq[0] = ldh8(Qf + qoff + qd * 8);
    aq[1] = ldh8(Qf + qoff + 32 + qd * 8);
  }
  f16x8 ones;
#pragma unroll
  for (int j = 0; j < 8; ++j) ones[j] = (_Float16)1.0f;

  // per-lane global bases (16B-aligned, coalesced in 64B row segments)
  const unsigned short* Kbase = Kf + ((size_t)bh * Tn + lr) * Dn + qd * 8;
  const unsigned short* Vbase = Vf + ((size_t)bh * Dn + lr) * Tn + qd * 8;

  f32x4 oacc[4] = {};
  float mrow = -1e30f, lsum = 0.f;

  for (int j0 = 0; j0 < Tn; j0 += 128) {
    // S^T = mfma(K, Q): K fragments loaded at use (compiler pipelines 2-3 deep
    // within its register budget; cross-wave TLP hides the rest)
    f32x4 s2[8];
#pragma unroll
    for (int ct = 0; ct < 8; ++ct) {
      const f16x8 k0 = ldh8(Kbase + (size_t)(j0 + ct * 16) * Dn);
      const f16x8 k1 = ldh8(Kbase + (size_t)(j0 + ct * 16) * Dn + 32);
      s2[ct] = f32x4{0.f, 0.f, 0.f, 0.f};
      s2[ct] = __builtin_amdgcn_mfma_f32_16x16x32_f16(k0, aq[0], s2[ct], 0, 0, 0);
      s2[ct] = __builtin_amdgcn_mfma_f32_16x16x32_f16(k1, aq[1], s2[ct], 0, 0, 0);
    }

    // row-local softmax (log2 domain; Q pre-scaled by 8*log2e)
    float tm = s2[0][0];
#pragma unroll
    for (int ct = 0; ct < 8; ++ct)
#pragma unroll
      for (int r = 0; r < 4; ++r) tm = fmaxf(tm, s2[ct][r]);
    tm = fmaxf(tm, __shfl_xor(tm, 16, 64));
    tm = fmaxf(tm, __shfl_xor(tm, 32, 64));
    const float mn = fmaxf(mrow, tm);
    const float alpha = exp2f(mrow - mn);
    mrow = mn;
#pragma unroll
    for (int ct = 0; ct < 8; ++ct)
#pragma unroll
      for (int r = 0; r < 4; ++r)
        s2[ct][r] = exp2f(s2[ct][r] - mrow);  // arg <= 0
#pragma unroll
    for (int nt = 0; nt < 4; ++nt)
#pragma unroll
      for (int r = 0; r < 4; ++r) oacc[nt][r] *= alpha;

    // pack P^T rows: lane owns 4 consecutive k -> b64 write (phase-floor banks)
#pragma unroll
    for (int ct = 0; ct < 8; ++ct) {
      uint2 d2;
      d2.x = pk2(s2[ct][0], s2[ct][1]);
      d2.y = pk2(s2[ct][2], s2[ct][3]);
      *reinterpret_cast<uint2*>(&myP[lr * PS + ct * 16 + qd * 4]) = d2;
    }

    // PV: O^T += mfma(V, P); V fragments loaded at use (per kcv);
    // rowsum via ones-MFMA (lane scalar at col q=lr)
    f32x4 sacc = {};
#pragma unroll
    for (int kcv = 0; kcv < 4; ++kcv) {
      const f16x8 pa = ldh8(&myP[lr * PS + kcv * 32 + qd * 8]);
#pragma unroll
      for (int nt = 0; nt < 4; ++nt) {
        const f16x8 bv = ldh8(Vbase + (size_t)(nt * 16) * Tn + j0 + kcv * 32);
        oacc[nt] = __builtin_amdgcn_mfma_f32_16x16x32_f16(bv, pa, oacc[nt], 0, 0, 0);
      }
      sacc = __builtin_amdgcn_mfma_f32_16x16x32_f16(ones, pa, sacc, 0, 0, 0);
    }
    lsum = lsum * alpha + sacc[0];
  }

  // epilogue: O^T normalized by per-lane lsum, packed 8B stores
  const int b = bh >> 4, h = bh & 15;
  const float inv = 1.0f / lsum;
  const int q = q0 + w * 16 + lr;
#pragma unroll
  for (int nt = 0; nt < 4; ++nt) {
    unsigned short o[4];
#pragma unroll
    for (int r = 0; r < 4; ++r) o[r] = f2h(oacc[nt][r] * inv);
    const int col = h * 64 + nt * 16 + qd * 4;
    *reinterpret_cast<u16x4*>(&AOf[((size_t)b * Tn + q) * En + col]) =
        u16x4{o[0], o[1], o[2], o[3]};
  }
}

// Out-projection: OUT f32; A = AO fp16, B = wout fp16 (pre-cast).
__global__ __launch_bounds__(256) void gemm_out(
    const unsigned short* __restrict__ A, const unsigned short* __restrict__ Bm,
    float* __restrict__ C, int M, int N, int K)
{
  __shared__ unsigned short shA[128 * 32];
  __shared__ unsigned short shB[128 * 32];
  const int tid = threadIdx.x;
  const int w = tid >> 6, L = tid & 63, qd = L >> 4, lr = L & 15;
  const int m0 = blockIdx.y * 128;
  const int n0 = blockIdx.x * 128;
  const int wm = (w >> 1) * 64, wn = (w & 1) * 64;

  f32x4 acc[4][4] = {};

  for (int k0 = 0; k0 < K; k0 += 32) {
#pragma unroll
    for (int p = 0; p < 2; ++p) {
      const int c = p * 256 + tid;
      const int row = c >> 2, slot = c & 3;
      const int base = (p * 4 + w) * 512;
      gld16(A + (size_t)(m0 + row) * K + k0 + slot * 8, &shA[base]);
      gld16(Bm + (size_t)(n0 + row) * K + k0 + slot * 8, &shB[base]);
    }
    __syncthreads();

    f16x8 af[4], bf[4];
#pragma unroll
    for (int mt = 0; mt < 4; ++mt)
      af[mt] = ldh8(&shA[(wm + mt * 16 + lr) * 32 + qd * 8]);
#pragma unroll
    for (int nt = 0; nt < 4; ++nt)
      bf[nt] = ldh8(&shB[(wn + nt * 16 + lr) * 32 + qd * 8]);
#pragma unroll
    for (int mt = 0; mt < 4; ++mt)
#pragma unroll
      for (int nt = 0; nt < 4; ++nt)
        acc[mt][nt] = __builtin_amdgcn_mfma_f32_16x16x32_f16(af[mt], bf[nt], acc[mt][nt], 0, 0, 0);
    __syncthreads();
  }

#pragma unroll
  for (int mt = 0; mt < 4; ++mt)
#pragma unroll
    for (int nt = 0; nt < 4; ++nt)
#pragma unroll
      for (int r = 0; r < 4; ++r) {
        const int m = m0 + wm + mt * 16 + qd * 4 + r;
        const int n = n0 + wn + nt * 16 + lr;
        C[(size_t)m * N + n] = acc[mt][nt][r];
      }
}

extern "C" void kernel_launch(void* const* d_in, const int* in_sizes, int n_in,
                              void* d_out, int out_size, void* d_ws, size_t ws_size,
                              hipStream_t stream) {
  (void)in_sizes; (void)n_in; (void)out_size; (void)ws_size;
  const float* x = (const float*)d_in[0];      // [2,2048,1024] f32
  const float* wqkv = (const float*)d_in[1];   // [3072,1024]  f32
  const float* wout = (const float*)d_in[2];   // [1024,1024]  f32
  float* out = (float*)d_out;                  // [2,2048,1024] f32

  const size_t elems = (size_t)Bn * Hn * Tn * Dn;  // 4M elems (8 MiB fp16)
  unsigned short* Qf = (unsigned short*)d_ws;
  unsigned short* Kf = Qf + elems;
  unsigned short* Vf = Kf + elems;
  unsigned short* AOf = Vf + elems;
  unsigned short* wf = AOf + elems;                // fp16 w_qkv, 3M
  unsigned short* wof = wf + (size_t)3 * En * En;  // fp16 wout, 1M (40 MiB)

  // d_out (16 MiB) doubles as scratch for x hi/lo; overwritten by gemm_out.
  unsigned short* xh = (unsigned short*)d_out;
  unsigned short* xl = xh + elems;

  const int M = Bn * Tn;  // 4096
  dim3 blk(256);
  split_f32_f16<<<dim3((int)(elems / 1024)), blk, 0, stream>>>(x, xh, xl);
  cvt_f32_f16<<<dim3(3 * En * En / 1024), blk, 0, stream>>>(wqkv, wf);
  cvt_f32_f16<<<dim3(En * En / 1024), blk, 0, stream>>>(wout, wof);
  gemm_qkv<<<dim3(24, M / 128), blk, 0, stream>>>(
      xh, xl, wf, Qf, Kf, Vf, M, En);
  attn_kernel<<<dim3(Tn / 64, Bn * Hn), blk, 0, stream>>>(Qf, Kf, Vf, AOf);
  gemm_out<<<dim3(En / 128, M / 128), blk, 0, stream>>>(
      AOf, wof, out, M, En, En);
}

// Round 11
// 266.689 us; speedup vs baseline: 1.9888x; 1.5416x over previous
//
#include <hip/hip_runtime.h>
#include <hip/hip_bf16.h>

typedef _Float16 f16x8 __attribute__((ext_vector_type(8)));
typedef unsigned short u16x8 __attribute__((ext_vector_type(8)));
typedef unsigned short u16x4 __attribute__((ext_vector_type(4)));
typedef float f32x4 __attribute__((ext_vector_type(4)));

static constexpr int Bn = 2;
static constexpr int Tn = 2048;
static constexpr int En = 1024;
static constexpr int Hn = 16;
static constexpr int Dn = 64;
#define LOG2E 1.44269504088896340736f

static constexpr int TS = 136;  // qkv epilogue transpose stride
static constexpr int PS = 40;   // attn P-chunk row stride (shorts): b64 writes
                                // land 2-way (free, m136); reads 16B-aligned

__device__ __forceinline__ unsigned short f2h(float x) {
  _Float16 h = (_Float16)x;
  return __builtin_bit_cast(unsigned short, h);
}
__device__ __forceinline__ float h2f(unsigned short u) {
  return (float)__builtin_bit_cast(_Float16, u);
}
__device__ __forceinline__ f16x8 ldh8(const unsigned short* p) {
  return __builtin_bit_cast(f16x8, *reinterpret_cast<const u16x8*>(p));
}
__device__ __forceinline__ unsigned int pk2(float a, float b) {
  return __builtin_bit_cast(unsigned int, __builtin_amdgcn_cvt_pkrtz(a, b));
}
// async global->LDS, 16B/lane; LDS dest must be wave-uniform base (+lane*16)
__device__ __forceinline__ void gld16(const void* g, void* l) {
  __builtin_amdgcn_global_load_lds(
      (__attribute__((address_space(1))) void*)(const_cast<void*>(g)),
      (__attribute__((address_space(3))) void*)(l), 16, 0, 0);
}

// fp16 hi/lo split: (hi + lo) == x to ~22 mantissa bits
__global__ __launch_bounds__(256) void split_f32_f16(
    const float* __restrict__ src, unsigned short* __restrict__ hi,
    unsigned short* __restrict__ lo)
{
  const int i = (blockIdx.x * 256 + threadIdx.x) * 4;
  const float4 v = *reinterpret_cast<const float4*>(src + i);
  ushort4 h, l;
  h.x = f2h(v.x); l.x = f2h(v.x - h2f(h.x));
  h.y = f2h(v.y); l.y = f2h(v.y - h2f(h.y));
  h.z = f2h(v.z); l.z = f2h(v.z - h2f(h.z));
  h.w = f2h(v.w); l.w = f2h(v.w - h2f(h.w));
  *reinterpret_cast<ushort4*>(hi + i) = h;
  *reinterpret_cast<ushort4*>(lo + i) = l;
}

__global__ __launch_bounds__(256) void cvt_f32_f16(
    const float* __restrict__ src, unsigned short* __restrict__ dst)
{
  const int i = (blockIdx.x * 256 + threadIdx.x) * 4;
  const float4 v = *reinterpret_cast<const float4*>(src + i);
  ushort4 u;
  u.x = f2h(v.x); u.y = f2h(v.y); u.z = f2h(v.z); u.w = f2h(v.w);
  *reinterpret_cast<ushort4*>(dst + i) = u;
}

// QKV GEMM, fp16: A = x as fp16 hi+lo (exact), B = w_qkv fp16. Q/K: 2 MFMA,
// V: 1 MFMA. Permuted column tiling c' = kk*1024 + hh*64 + dd
// (w_qkv row n = dd*48+kk*16+hh). Outputs fp16: Q(x8*log2e),K [b,h,t,d]; V [b,h,d,t].
__global__ __launch_bounds__(256) void gemm_qkv(
    const unsigned short* __restrict__ xh, const unsigned short* __restrict__ xl,
    const unsigned short* __restrict__ wf,
    unsigned short* __restrict__ Qf, unsigned short* __restrict__ Kf,
    unsigned short* __restrict__ Vf, int M, int K)
{
  __shared__ unsigned short smem[128 * TS];  // 34816 B; reused by epilogue
  unsigned short* shAh = smem;               // 128x32 each, unpadded
  unsigned short* shAl = smem + 4096;
  unsigned short* shB = smem + 8192;

  const int tid = threadIdx.x;
  const int w = tid >> 6, L = tid & 63, qd = L >> 4, lr = L & 15;
  const int m0 = blockIdx.y * 128;
  const int kk = blockIdx.x >> 3;          // 0=Q 1=K 2=V (uniform per block)
  const int hh0 = (blockIdx.x & 7) * 2;    // two heads per block
  const int wm = (w >> 1) * 64, wn = (w & 1) * 64;

  f32x4 acc[4][4] = {};

  for (int k0 = 0; k0 < K; k0 += 32) {
#pragma unroll
    for (int p = 0; p < 2; ++p) {
      const int c = p * 256 + tid;
      const int row = c >> 2, slot = c & 3;
      const int dd = row & 63, hl = row >> 6;
      const int nB = dd * 48 + kk * 16 + hh0 + hl;
      const size_t aoff = (size_t)(m0 + row) * K + k0 + slot * 8;
      const size_t boff = (size_t)nB * K + k0 + slot * 8;
      const int base = (p * 4 + w) * 512;  // wave-uniform LDS base (shorts)
      gld16(xh + aoff, &shAh[base]);
      gld16(wf + boff, &shB[base]);
      if (kk < 2) gld16(xl + aoff, &shAl[base]);
    }
    __syncthreads();

    f16x8 afh[4], bf[4];
#pragma unroll
    for (int mt = 0; mt < 4; ++mt)
      afh[mt] = ldh8(&shAh[(wm + mt * 16 + lr) * 32 + qd * 8]);
#pragma unroll
    for (int nt = 0; nt < 4; ++nt)
      bf[nt] = ldh8(&shB[(wn + nt * 16 + lr) * 32 + qd * 8]);
    if (kk < 2) {
      f16x8 afl[4];
#pragma unroll
      for (int mt = 0; mt < 4; ++mt)
        afl[mt] = ldh8(&shAl[(wm + mt * 16 + lr) * 32 + qd * 8]);
#pragma unroll
      for (int mt = 0; mt < 4; ++mt)
#pragma unroll
        for (int nt = 0; nt < 4; ++nt) {
          acc[mt][nt] = __builtin_amdgcn_mfma_f32_16x16x32_f16(afh[mt], bf[nt], acc[mt][nt], 0, 0, 0);
          acc[mt][nt] = __builtin_amdgcn_mfma_f32_16x16x32_f16(afl[mt], bf[nt], acc[mt][nt], 0, 0, 0);
        }
    } else {
#pragma unroll
      for (int mt = 0; mt < 4; ++mt)
#pragma unroll
        for (int nt = 0; nt < 4; ++nt)
          acc[mt][nt] = __builtin_amdgcn_mfma_f32_16x16x32_f16(afh[mt], bf[nt], acc[mt][nt], 0, 0, 0);
    }
    __syncthreads();
  }

  // epilogue: fp16 into LDS transpose buffer -> coalesced 16B stores
  const int b = m0 >> 11;
  const int t0 = m0 & (Tn - 1);
  // fold *sqrt(d)*log2(e) into Q so attn softmax is exp2(s - m) directly
  const float qscale = (kk == 0) ? 8.0f * LOG2E : 1.0f;
#pragma unroll
  for (int mt = 0; mt < 4; ++mt)
#pragma unroll
    for (int nt = 0; nt < 4; ++nt)
#pragma unroll
      for (int r = 0; r < 4; ++r) {
        const int ml = wm + mt * 16 + qd * 4 + r;  // C/D row=(lane>>4)*4+reg
        const int cl = wn + nt * 16 + lr;          // C/D col=lane&15
        smem[ml * TS + cl] = f2h(acc[mt][nt][r] * qscale);
      }
  __syncthreads();

  unsigned short* dst = (kk == 0) ? Qf : (kk == 1) ? Kf : Vf;
  if (kk < 2) {
#pragma unroll
    for (int p = 0; p < 8; ++p) {
      const int s = p * 256 + tid;
      const int tl = s >> 4, sub = s & 15;
      const int hl = sub >> 3, oct = sub & 7;
      const u16x8 v = *reinterpret_cast<const u16x8*>(&smem[tl * TS + hl * 64 + oct * 8]);
      *reinterpret_cast<u16x8*>(
          dst + ((size_t)(b * Hn + hh0 + hl) * Tn + t0 + tl) * Dn + oct * 8) = v;
    }
  } else {
#pragma unroll
    for (int p = 0; p < 8; ++p) {
      const int s = p * 256 + tid;
      const int cl = s >> 4, oct = s & 15;
      const int hl = cl >> 6, dd = cl & 63;
      u16x8 v;
#pragma unroll
      for (int j = 0; j < 8; ++j) v[j] = smem[(oct * 8 + j) * TS + cl];
      *reinterpret_cast<u16x8*>(
          dst + ((size_t)((b * Hn + hh0 + hl) * Dn + dd)) * Tn + t0 + oct * 8) = v;
    }
  }
}

// Flash attention: hybrid of the two measured-good structures.
//  - K/V staged global->LDS via global_load_lds (ZERO VGPR cost — the register
//    file cannot hold a K/V pipeline: (256,4) spilled 728 MB [r8], loads-at-use
//    starved at 56 VGPR [r10], arrays cap at 2 blk/CU [r5]).
//  - Swapped-operand QK^T (S^T lane-local, q=lane&15): softmax = 31 fmax +
//    2 shfl + 32 exp2 in log2-domain (Q pre-scaled 8*log2e), vs r1's serial
//    path that made VALUBusy 49%.
//  - Chunked packed P: per 32-col chunk, 2x cvt_pkrtz + b64 write (PS=40,
//    2-way-free), read back as PV A-op fragment. No barrier needed (same-wave).
//  - 64-row blocks, grid 1024, LDS 37 KB, ~110 VGPR -> 4 blocks/CU.
// Qf(x8*log2e),Kf: [b,h,t,d]  Vf: [b,h,d,t]  AO: fp16, O^T epilogue.
__global__ __launch_bounds__(256, 2) void attn_kernel(
    const unsigned short* __restrict__ Qf, const unsigned short* __restrict__ Kf,
    const unsigned short* __restrict__ Vf, unsigned short* __restrict__ AOf)
{
  __shared__ unsigned short shK[2 * 128 * 32];  // [kc][j row][32]  16 KB
  __shared__ unsigned short shV[4 * 64 * 32];   // [kcv][dd][32]    16 KB
  __shared__ unsigned short shP[4 * 16 * PS];   // per-wave 16x32 chunk, 5 KB
  const int tid = threadIdx.x;
  const int w = tid >> 6, L = tid & 63, qd = L >> 4, lr = L & 15;
  const int q0 = blockIdx.x * 64;
  const int bh = blockIdx.y;
  unsigned short* myP = &shP[w * 16 * PS];

  f16x8 aq[2];
  {
    const size_t qoff = ((size_t)bh * Tn + q0 + w * 16 + lr) * Dn;
    aq[0] = ldh8(Qf + qoff + qd * 8);
    aq[1] = ldh8(Qf + qoff + 32 + qd * 8);
  }
  f16x8 ones;
#pragma unroll
  for (int j = 0; j < 8; ++j) ones[j] = (_Float16)1.0f;

  f32x4 oacc[4] = {};
  float mrow = -1e30f, lsum = 0.f;

  for (int j0 = 0; j0 < Tn; j0 += 128) {
    // stage K tile (128 j x 64 d) as [kc][row][32]; wave w owns rows w*16..+15
    // of each half -> LDS dest wave-uniform, lane layout linear (verified r0)
#pragma unroll
    for (int p = 0; p < 4; ++p) {
      const int kc = p >> 1, half = p & 1;
      const int row = half * 64 + (tid >> 2);
      const int slot = tid & 3;
      gld16(Kf + ((size_t)bh * Tn + j0 + row) * Dn + kc * 32 + slot * 8,
            &shK[kc * 4096 + (half * 64 + w * 16) * 32]);
    }
    // stage V tile (64 d x 128 t) as [kcv][dd][32]
#pragma unroll
    for (int p = 0; p < 4; ++p) {
      const int dd = tid >> 2, slot = tid & 3;
      gld16(Vf + ((size_t)bh * Dn + dd) * Tn + j0 + p * 32 + slot * 8,
            &shV[p * 2048 + (w * 16) * 32]);
    }
    __syncthreads();

    // S^T = mfma(K, Q): lane holds S'[q=lr][k = ct*16 + qd*4 + r]
    f32x4 s2[8];
#pragma unroll
    for (int ct = 0; ct < 8; ++ct) {
      const int rk = ct * 16 + lr;
      s2[ct] = f32x4{0.f, 0.f, 0.f, 0.f};
#pragma unroll
      for (int kc = 0; kc < 2; ++kc) {
        const f16x8 bk = ldh8(&shK[kc * 4096 + rk * 32 + qd * 8]);
        s2[ct] = __builtin_amdgcn_mfma_f32_16x16x32_f16(bk, aq[kc], s2[ct], 0, 0, 0);
      }
    }

    // row-local softmax (log2 domain; Q pre-scaled by 8*log2e)
    float tm = s2[0][0];
#pragma unroll
    for (int ct = 0; ct < 8; ++ct)
#pragma unroll
      for (int r = 0; r < 4; ++r) tm = fmaxf(tm, s2[ct][r]);
    tm = fmaxf(tm, __shfl_xor(tm, 16, 64));
    tm = fmaxf(tm, __shfl_xor(tm, 32, 64));
    const float mn = fmaxf(mrow, tm);
    const float alpha = exp2f(mrow - mn);
    mrow = mn;
#pragma unroll
    for (int ct = 0; ct < 8; ++ct)
#pragma unroll
      for (int r = 0; r < 4; ++r)
        s2[ct][r] = exp2f(s2[ct][r] - mrow);  // arg <= 0
#pragma unroll
    for (int nt = 0; nt < 4; ++nt)
#pragma unroll
      for (int r = 0; r < 4; ++r) oacc[nt][r] *= alpha;

    // PV chunked: per 32-col chunk, pack P rows (2x b64/lane), read A-op
    // fragment back, 4 V-MFMA + rowsum ones-MFMA. Same-wave RAW/WAR on myP
    // handled by lgkmcnt (r0-verified pattern, no barrier).
    f32x4 sacc = {};
#pragma unroll
    for (int kcv = 0; kcv < 4; ++kcv) {
#pragma unroll
      for (int c2 = 0; c2 < 2; ++c2) {
        const int ct = kcv * 2 + c2;
        uint2 d2;
        d2.x = pk2(s2[ct][0], s2[ct][1]);
        d2.y = pk2(s2[ct][2], s2[ct][3]);
        *reinterpret_cast<uint2*>(&myP[lr * PS + c2 * 16 + qd * 4]) = d2;
      }
      const f16x8 pa = ldh8(&myP[lr * PS + qd * 8]);
#pragma unroll
      for (int nt = 0; nt < 4; ++nt) {
        const f16x8 bv = ldh8(&shV[kcv * 2048 + (nt * 16 + lr) * 32 + qd * 8]);
        oacc[nt] = __builtin_amdgcn_mfma_f32_16x16x32_f16(bv, pa, oacc[nt], 0, 0, 0);
      }
      sacc = __builtin_amdgcn_mfma_f32_16x16x32_f16(ones, pa, sacc, 0, 0, 0);
    }
    lsum = lsum * alpha + sacc[0];
    __syncthreads();
  }

  // epilogue: O^T normalized by per-lane lsum, packed 8B stores
  const int b = bh >> 4, h = bh & 15;
  const float inv = 1.0f / lsum;
  const int q = q0 + w * 16 + lr;
#pragma unroll
  for (int nt = 0; nt < 4; ++nt) {
    unsigned short o[4];
#pragma unroll
    for (int r = 0; r < 4; ++r) o[r] = f2h(oacc[nt][r] * inv);
    const int col = h * 64 + nt * 16 + qd * 4;
    *reinterpret_cast<u16x4*>(&AOf[((size_t)b * Tn + q) * En + col]) =
        u16x4{o[0], o[1], o[2], o[3]};
  }
}

// Out-projection: OUT f32; A = AO fp16, B = wout fp16 (pre-cast).
__global__ __launch_bounds__(256) void gemm_out(
    const unsigned short* __restrict__ A, const unsigned short* __restrict__ Bm,
    float* __restrict__ C, int M, int N, int K)
{
  __shared__ unsigned short shA[128 * 32];
  __shared__ unsigned short shB[128 * 32];
  const int tid = threadIdx.x;
  const int w = tid >> 6, L = tid & 63, qd = L >> 4, lr = L & 15;
  const int m0 = blockIdx.y * 128;
  const int n0 = blockIdx.x * 128;
  const int wm = (w >> 1) * 64, wn = (w & 1) * 64;

  f32x4 acc[4][4] = {};

  for (int k0 = 0; k0 < K; k0 += 32) {
#pragma unroll
    for (int p = 0; p < 2; ++p) {
      const int c = p * 256 + tid;
      const int row = c >> 2, slot = c & 3;
      const int base = (p * 4 + w) * 512;
      gld16(A + (size_t)(m0 + row) * K + k0 + slot * 8, &shA[base]);
      gld16(Bm + (size_t)(n0 + row) * K + k0 + slot * 8, &shB[base]);
    }
    __syncthreads();

    f16x8 af[4], bf[4];
#pragma unroll
    for (int mt = 0; mt < 4; ++mt)
      af[mt] = ldh8(&shA[(wm + mt * 16 + lr) * 32 + qd * 8]);
#pragma unroll
    for (int nt = 0; nt < 4; ++nt)
      bf[nt] = ldh8(&shB[(wn + nt * 16 + lr) * 32 + qd * 8]);
#pragma unroll
    for (int mt = 0; mt < 4; ++mt)
#pragma unroll
      for (int nt = 0; nt < 4; ++nt)
        acc[mt][nt] = __builtin_amdgcn_mfma_f32_16x16x32_f16(af[mt], bf[nt], acc[mt][nt], 0, 0, 0);
    __syncthreads();
  }

#pragma unroll
  for (int mt = 0; mt < 4; ++mt)
#pragma unroll
    for (int nt = 0; nt < 4; ++nt)
#pragma unroll
      for (int r = 0; r < 4; ++r) {
        const int m = m0 + wm + mt * 16 + qd * 4 + r;
        const int n = n0 + wn + nt * 16 + lr;
        C[(size_t)m * N + n] = acc[mt][nt][r];
      }
}

extern "C" void kernel_launch(void* const* d_in, const int* in_sizes, int n_in,
                              void* d_out, int out_size, void* d_ws, size_t ws_size,
                              hipStream_t stream) {
  (void)in_sizes; (void)n_in; (void)out_size; (void)ws_size;
  const float* x = (const float*)d_in[0];      // [2,2048,1024] f32
  const float* wqkv = (const float*)d_in[1];   // [3072,1024]  f32
  const float* wout = (const float*)d_in[2];   // [1024,1024]  f32
  float* out = (float*)d_out;                  // [2,2048,1024] f32

  const size_t elems = (size_t)Bn * Hn * Tn * Dn;  // 4M elems (8 MiB fp16)
  unsigned short* Qf = (unsigned short*)d_ws;
  unsigned short* Kf = Qf + elems;
  unsigned short* Vf = Kf + elems;
  unsigned short* AOf = Vf + elems;
  unsigned short* wf = AOf + elems;                // fp16 w_qkv, 3M
  unsigned short* wof = wf + (size_t)3 * En * En;  // fp16 wout, 1M (40 MiB)

  // d_out (16 MiB) doubles as scratch for x hi/lo; overwritten by gemm_out.
  unsigned short* xh = (unsigned short*)d_out;
  unsigned short* xl = xh + elems;

  const int M = Bn * Tn;  // 4096
  dim3 blk(256);
  split_f32_f16<<<dim3((int)(elems / 1024)), blk, 0, stream>>>(x, xh, xl);
  cvt_f32_f16<<<dim3(3 * En * En / 1024), blk, 0, stream>>>(wqkv, wf);
  cvt_f32_f16<<<dim3(En * En / 1024), blk, 0, stream>>>(wout, wof);
  gemm_qkv<<<dim3(24, M / 128), blk, 0, stream>>>(
      xh, xl, wf, Qf, Kf, Vf, M, En);
  attn_kernel<<<dim3(Tn / 64, Bn * Hn), blk, 0, stream>>>(Qf, Kf, Vf, AOf);
  gemm_out<<<dim3(En / 128, M / 128), blk, 0, stream>>>(
      AOf, wof, out, M, En, En);
}

// Round 12
// 245.731 us; speedup vs baseline: 2.1584x; 1.0853x over previous
//
#include <hip/hip_runtime.h>
#include <hip/hip_bf16.h>

typedef _Float16 f16x8 __attribute__((ext_vector_type(8)));
typedef unsigned short u16x8 __attribute__((ext_vector_type(8)));
typedef unsigned short u16x4 __attribute__((ext_vector_type(4)));
typedef float f32x4 __attribute__((ext_vector_type(4)));

static constexpr int Bn = 2;
static constexpr int Tn = 2048;
static constexpr int En = 1024;
static constexpr int Hn = 16;
static constexpr int Dn = 64;
#define LOG2E 1.44269504088896340736f

static constexpr int TS = 136;  // qkv epilogue transpose stride
static constexpr int PS = 40;   // attn P-chunk row stride (shorts): b64 writes
                                // land 2-way (free, m136); reads 16B-aligned

__device__ __forceinline__ unsigned short f2h(float x) {
  _Float16 h = (_Float16)x;
  return __builtin_bit_cast(unsigned short, h);
}
__device__ __forceinline__ float h2f(unsigned short u) {
  return (float)__builtin_bit_cast(_Float16, u);
}
__device__ __forceinline__ f16x8 ldh8(const unsigned short* p) {
  return __builtin_bit_cast(f16x8, *reinterpret_cast<const u16x8*>(p));
}
__device__ __forceinline__ unsigned int pk2(float a, float b) {
  return __builtin_bit_cast(unsigned int, __builtin_amdgcn_cvt_pkrtz(a, b));
}
// async global->LDS, 16B/lane; LDS dest must be wave-uniform base (+lane*16)
__device__ __forceinline__ void gld16(const void* g, void* l) {
  __builtin_amdgcn_global_load_lds(
      (__attribute__((address_space(1))) void*)(const_cast<void*>(g)),
      (__attribute__((address_space(3))) void*)(l), 16, 0, 0);
}

// fp16 hi/lo split: (hi + lo) == x to ~22 mantissa bits
__global__ __launch_bounds__(256) void split_f32_f16(
    const float* __restrict__ src, unsigned short* __restrict__ hi,
    unsigned short* __restrict__ lo)
{
  const int i = (blockIdx.x * 256 + threadIdx.x) * 4;
  const float4 v = *reinterpret_cast<const float4*>(src + i);
  ushort4 h, l;
  h.x = f2h(v.x); l.x = f2h(v.x - h2f(h.x));
  h.y = f2h(v.y); l.y = f2h(v.y - h2f(h.y));
  h.z = f2h(v.z); l.z = f2h(v.z - h2f(h.z));
  h.w = f2h(v.w); l.w = f2h(v.w - h2f(h.w));
  *reinterpret_cast<ushort4*>(hi + i) = h;
  *reinterpret_cast<ushort4*>(lo + i) = l;
}

__global__ __launch_bounds__(256) void cvt_f32_f16(
    const float* __restrict__ src, unsigned short* __restrict__ dst)
{
  const int i = (blockIdx.x * 256 + threadIdx.x) * 4;
  const float4 v = *reinterpret_cast<const float4*>(src + i);
  ushort4 u;
  u.x = f2h(v.x); u.y = f2h(v.y); u.z = f2h(v.z); u.w = f2h(v.w);
  *reinterpret_cast<ushort4*>(dst + i) = u;
}

// QKV GEMM, fp16: A = x as fp16 hi+lo (exact), B = w_qkv fp16. Q/K: 2 MFMA,
// V: 1 MFMA. Permuted column tiling c' = kk*1024 + hh*64 + dd
// (w_qkv row n = dd*48+kk*16+hh). Outputs fp16: Q(x8*log2e),K [b,h,t,d]; V [b,h,d,t].
// THIS ROUND: 2-phase double-buffered K-loop (T3-lite): issue next tile's
// global_load_lds into buf^1 BEFORE computing from buf, ONE __syncthreads per
// iter (its vmcnt(0) drain lands the prefetch, which had the whole compute
// phase in flight). Was: stage -> drain -> compute serial, 2 barriers/iter,
// MfmaUtil 19% (r11: staging ~1100 cyc/iter vs compute ~465, run in series).
__global__ __launch_bounds__(256) void gemm_qkv(
    const unsigned short* __restrict__ xh, const unsigned short* __restrict__ xl,
    const unsigned short* __restrict__ wf,
    unsigned short* __restrict__ Qf, unsigned short* __restrict__ Kf,
    unsigned short* __restrict__ Vf, int M, int K)
{
  // 2 x (Ah 4096 | Al 4096 | B 4096 shorts) = 49152 B; epilogue reuses [0..17408)
  __shared__ unsigned short smem[2 * 12288];

  const int tid = threadIdx.x;
  const int w = tid >> 6, L = tid & 63, qd = L >> 4, lr = L & 15;
  const int m0 = blockIdx.y * 128;
  const int kk = blockIdx.x >> 3;          // 0=Q 1=K 2=V (uniform per block)
  const int hh0 = (blockIdx.x & 7) * 2;    // two heads per block
  const int wm = (w >> 1) * 64, wn = (w & 1) * 64;

  // per-thread staging addresses (two 16B phases); k0 added in-loop
  size_t aoffs[2], boffs[2];
  int lbase[2];
#pragma unroll
  for (int p = 0; p < 2; ++p) {
    const int c = p * 256 + tid;
    const int row = c >> 2, slot = c & 3;
    const int dd = row & 63, hl = row >> 6;
    aoffs[p] = (size_t)(m0 + row) * K + slot * 8;
    boffs[p] = (size_t)(dd * 48 + kk * 16 + hh0 + hl) * K + slot * 8;
    lbase[p] = (p * 4 + w) * 512;  // wave-uniform LDS base (shorts)
  }

  f32x4 acc[4][4] = {};

  // prologue: stage tile 0 into buf 0
#pragma unroll
  for (int p = 0; p < 2; ++p) {
    gld16(xh + aoffs[p], &smem[lbase[p]]);
    gld16(wf + boffs[p], &smem[8192 + lbase[p]]);
    if (kk < 2) gld16(xl + aoffs[p], &smem[4096 + lbase[p]]);
  }
  __syncthreads();

  int buf = 0;
  for (int k0 = 0; k0 < K; k0 += 32) {
    // issue next tile's staging into the other buffer (overlaps compute)
    if (k0 + 32 < K) {
      const int nb = (buf ^ 1) * 12288;
#pragma unroll
      for (int p = 0; p < 2; ++p) {
        gld16(xh + aoffs[p] + k0 + 32, &smem[nb + lbase[p]]);
        gld16(wf + boffs[p] + k0 + 32, &smem[nb + 8192 + lbase[p]]);
        if (kk < 2) gld16(xl + aoffs[p] + k0 + 32, &smem[nb + 4096 + lbase[p]]);
      }
    }

    const int cb = buf * 12288;
    f16x8 afh[4], bf[4];
#pragma unroll
    for (int mt = 0; mt < 4; ++mt)
      afh[mt] = ldh8(&smem[cb + (wm + mt * 16 + lr) * 32 + qd * 8]);
#pragma unroll
    for (int nt = 0; nt < 4; ++nt)
      bf[nt] = ldh8(&smem[cb + 8192 + (wn + nt * 16 + lr) * 32 + qd * 8]);
    if (kk < 2) {
      f16x8 afl[4];
#pragma unroll
      for (int mt = 0; mt < 4; ++mt)
        afl[mt] = ldh8(&smem[cb + 4096 + (wm + mt * 16 + lr) * 32 + qd * 8]);
#pragma unroll
      for (int mt = 0; mt < 4; ++mt)
#pragma unroll
        for (int nt = 0; nt < 4; ++nt) {
          acc[mt][nt] = __builtin_amdgcn_mfma_f32_16x16x32_f16(afh[mt], bf[nt], acc[mt][nt], 0, 0, 0);
          acc[mt][nt] = __builtin_amdgcn_mfma_f32_16x16x32_f16(afl[mt], bf[nt], acc[mt][nt], 0, 0, 0);
        }
    } else {
#pragma unroll
      for (int mt = 0; mt < 4; ++mt)
#pragma unroll
        for (int nt = 0; nt < 4; ++nt)
          acc[mt][nt] = __builtin_amdgcn_mfma_f32_16x16x32_f16(afh[mt], bf[nt], acc[mt][nt], 0, 0, 0);
    }
    // single barrier: drains this wave's vmcnt (next tile landed) and fences
    // everyone's ds_reads of buf before it is overwritten two iters later
    __syncthreads();
    buf ^= 1;
  }

  // epilogue: fp16 into LDS transpose buffer -> coalesced 16B stores
  const int b = m0 >> 11;
  const int t0 = m0 & (Tn - 1);
  // fold *sqrt(d)*log2(e) into Q so attn softmax is exp2(s - m) directly
  const float qscale = (kk == 0) ? 8.0f * LOG2E : 1.0f;
#pragma unroll
  for (int mt = 0; mt < 4; ++mt)
#pragma unroll
    for (int nt = 0; nt < 4; ++nt)
#pragma unroll
      for (int r = 0; r < 4; ++r) {
        const int ml = wm + mt * 16 + qd * 4 + r;  // C/D row=(lane>>4)*4+reg
        const int cl = wn + nt * 16 + lr;          // C/D col=lane&15
        smem[ml * TS + cl] = f2h(acc[mt][nt][r] * qscale);
      }
  __syncthreads();

  unsigned short* dst = (kk == 0) ? Qf : (kk == 1) ? Kf : Vf;
  if (kk < 2) {
#pragma unroll
    for (int p = 0; p < 8; ++p) {
      const int s = p * 256 + tid;
      const int tl = s >> 4, sub = s & 15;
      const int hl = sub >> 3, oct = sub & 7;
      const u16x8 v = *reinterpret_cast<const u16x8*>(&smem[tl * TS + hl * 64 + oct * 8]);
      *reinterpret_cast<u16x8*>(
          dst + ((size_t)(b * Hn + hh0 + hl) * Tn + t0 + tl) * Dn + oct * 8) = v;
    }
  } else {
#pragma unroll
    for (int p = 0; p < 8; ++p) {
      const int s = p * 256 + tid;
      const int cl = s >> 4, oct = s & 15;
      const int hl = cl >> 6, dd = cl & 63;
      u16x8 v;
#pragma unroll
      for (int j = 0; j < 8; ++j) v[j] = smem[(oct * 8 + j) * TS + cl];
      *reinterpret_cast<u16x8*>(
          dst + ((size_t)((b * Hn + hh0 + hl) * Dn + dd)) * Tn + t0 + oct * 8) = v;
    }
  }
}

// Flash attention (r11 measured-good, unchanged):
//  - K/V staged global->LDS via global_load_lds (zero VGPR cost).
//  - Swapped-operand QK^T (S^T lane-local, q=lane&15): softmax = 31 fmax +
//    2 shfl + 32 exp2 in log2-domain (Q pre-scaled 8*log2e).
//  - Chunked packed P: per 32-col chunk, 2x cvt_pkrtz + b64 write (PS=40),
//    read back as PV A-op fragment (same-wave, lgkmcnt-ordered, no barrier).
//  - 64-row blocks, grid 1024, LDS 37 KB.
// Qf(x8*log2e),Kf: [b,h,t,d]  Vf: [b,h,d,t]  AO: fp16, O^T epilogue.
__global__ __launch_bounds__(256, 2) void attn_kernel(
    const unsigned short* __restrict__ Qf, const unsigned short* __restrict__ Kf,
    const unsigned short* __restrict__ Vf, unsigned short* __restrict__ AOf)
{
  __shared__ unsigned short shK[2 * 128 * 32];  // [kc][j row][32]  16 KB
  __shared__ unsigned short shV[4 * 64 * 32];   // [kcv][dd][32]    16 KB
  __shared__ unsigned short shP[4 * 16 * PS];   // per-wave 16x32 chunk, 5 KB
  const int tid = threadIdx.x;
  const int w = tid >> 6, L = tid & 63, qd = L >> 4, lr = L & 15;
  const int q0 = blockIdx.x * 64;
  const int bh = blockIdx.y;
  unsigned short* myP = &shP[w * 16 * PS];

  f16x8 aq[2];
  {
    const size_t qoff = ((size_t)bh * Tn + q0 + w * 16 + lr) * Dn;
    aq[0] = ldh8(Qf + qoff + qd * 8);
    aq[1] = ldh8(Qf + qoff + 32 + qd * 8);
  }
  f16x8 ones;
#pragma unroll
  for (int j = 0; j < 8; ++j) ones[j] = (_Float16)1.0f;

  f32x4 oacc[4] = {};
  float mrow = -1e30f, lsum = 0.f;

  for (int j0 = 0; j0 < Tn; j0 += 128) {
    // stage K tile (128 j x 64 d) as [kc][row][32]
#pragma unroll
    for (int p = 0; p < 4; ++p) {
      const int kc = p >> 1, half = p & 1;
      const int row = half * 64 + (tid >> 2);
      const int slot = tid & 3;
      gld16(Kf + ((size_t)bh * Tn + j0 + row) * Dn + kc * 32 + slot * 8,
            &shK[kc * 4096 + (half * 64 + w * 16) * 32]);
    }
    // stage V tile (64 d x 128 t) as [kcv][dd][32]
#pragma unroll
    for (int p = 0; p < 4; ++p) {
      const int dd = tid >> 2, slot = tid & 3;
      gld16(Vf + ((size_t)bh * Dn + dd) * Tn + j0 + p * 32 + slot * 8,
            &shV[p * 2048 + (w * 16) * 32]);
    }
    __syncthreads();

    // S^T = mfma(K, Q): lane holds S'[q=lr][k = ct*16 + qd*4 + r]
    f32x4 s2[8];
#pragma unroll
    for (int ct = 0; ct < 8; ++ct) {
      const int rk = ct * 16 + lr;
      s2[ct] = f32x4{0.f, 0.f, 0.f, 0.f};
#pragma unroll
      for (int kc = 0; kc < 2; ++kc) {
        const f16x8 bk = ldh8(&shK[kc * 4096 + rk * 32 + qd * 8]);
        s2[ct] = __builtin_amdgcn_mfma_f32_16x16x32_f16(bk, aq[kc], s2[ct], 0, 0, 0);
      }
    }

    // row-local softmax (log2 domain; Q pre-scaled by 8*log2e)
    float tm = s2[0][0];
#pragma unroll
    for (int ct = 0; ct < 8; ++ct)
#pragma unroll
      for (int r = 0; r < 4; ++r) tm = fmaxf(tm, s2[ct][r]);
    tm = fmaxf(tm, __shfl_xor(tm, 16, 64));
    tm = fmaxf(tm, __shfl_xor(tm, 32, 64));
    const float mn = fmaxf(mrow, tm);
    const float alpha = exp2f(mrow - mn);
    mrow = mn;
#pragma unroll
    for (int ct = 0; ct < 8; ++ct)
#pragma unroll
      for (int r = 0; r < 4; ++r)
        s2[ct][r] = exp2f(s2[ct][r] - mrow);  // arg <= 0
#pragma unroll
    for (int nt = 0; nt < 4; ++nt)
#pragma unroll
      for (int r = 0; r < 4; ++r) oacc[nt][r] *= alpha;

    // PV chunked: per 32-col chunk, pack P rows (2x b64/lane), read A-op
    // fragment back, 4 V-MFMA + rowsum ones-MFMA (same-wave lgkmcnt ordering)
    f32x4 sacc = {};
#pragma unroll
    for (int kcv = 0; kcv < 4; ++kcv) {
#pragma unroll
      for (int c2 = 0; c2 < 2; ++c2) {
        const int ct = kcv * 2 + c2;
        uint2 d2;
        d2.x = pk2(s2[ct][0], s2[ct][1]);
        d2.y = pk2(s2[ct][2], s2[ct][3]);
        *reinterpret_cast<uint2*>(&myP[lr * PS + c2 * 16 + qd * 4]) = d2;
      }
      const f16x8 pa = ldh8(&myP[lr * PS + qd * 8]);
#pragma unroll
      for (int nt = 0; nt < 4; ++nt) {
        const f16x8 bv = ldh8(&shV[kcv * 2048 + (nt * 16 + lr) * 32 + qd * 8]);
        oacc[nt] = __builtin_amdgcn_mfma_f32_16x16x32_f16(bv, pa, oacc[nt], 0, 0, 0);
      }
      sacc = __builtin_amdgcn_mfma_f32_16x16x32_f16(ones, pa, sacc, 0, 0, 0);
    }
    lsum = lsum * alpha + sacc[0];
    __syncthreads();
  }

  // epilogue: O^T normalized by per-lane lsum, packed 8B stores
  const int b = bh >> 4, h = bh & 15;
  const float inv = 1.0f / lsum;
  const int q = q0 + w * 16 + lr;
#pragma unroll
  for (int nt = 0; nt < 4; ++nt) {
    unsigned short o[4];
#pragma unroll
    for (int r = 0; r < 4; ++r) o[r] = f2h(oacc[nt][r] * inv);
    const int col = h * 64 + nt * 16 + qd * 4;
    *reinterpret_cast<u16x4*>(&AOf[((size_t)b * Tn + q) * En + col]) =
        u16x4{o[0], o[1], o[2], o[3]};
  }
}

// Out-projection: OUT f32; A = AO fp16, B = wout fp16 (pre-cast).
__global__ __launch_bounds__(256) void gemm_out(
    const unsigned short* __restrict__ A, const unsigned short* __restrict__ Bm,
    float* __restrict__ C, int M, int N, int K)
{
  __shared__ unsigned short shA[128 * 32];
  __shared__ unsigned short shB[128 * 32];
  const int tid = threadIdx.x;
  const int w = tid >> 6, L = tid & 63, qd = L >> 4, lr = L & 15;
  const int m0 = blockIdx.y * 128;
  const int n0 = blockIdx.x * 128;
  const int wm = (w >> 1) * 64, wn = (w & 1) * 64;

  f32x4 acc[4][4] = {};

  for (int k0 = 0; k0 < K; k0 += 32) {
#pragma unroll
    for (int p = 0; p < 2; ++p) {
      const int c = p * 256 + tid;
      const int row = c >> 2, slot = c & 3;
      const int base = (p * 4 + w) * 512;
      gld16(A + (size_t)(m0 + row) * K + k0 + slot * 8, &shA[base]);
      gld16(Bm + (size_t)(n0 + row) * K + k0 + slot * 8, &shB[base]);
    }
    __syncthreads();

    f16x8 af[4], bf[4];
#pragma unroll
    for (int mt = 0; mt < 4; ++mt)
      af[mt] = ldh8(&shA[(wm + mt * 16 + lr) * 32 + qd * 8]);
#pragma unroll
    for (int nt = 0; nt < 4; ++nt)
      bf[nt] = ldh8(&shB[(wn + nt * 16 + lr) * 32 + qd * 8]);
#pragma unroll
    for (int mt = 0; mt < 4; ++mt)
#pragma unroll
      for (int nt = 0; nt < 4; ++nt)
        acc[mt][nt] = __builtin_amdgcn_mfma_f32_16x16x32_f16(af[mt], bf[nt], acc[mt][nt], 0, 0, 0);
    __syncthreads();
  }

#pragma unroll
  for (int mt = 0; mt < 4; ++mt)
#pragma unroll
    for (int nt = 0; nt < 4; ++nt)
#pragma unroll
      for (int r = 0; r < 4; ++r) {
        const int m = m0 + wm + mt * 16 + qd * 4 + r;
        const int n = n0 + wn + nt * 16 + lr;
        C[(size_t)m * N + n] = acc[mt][nt][r];
      }
}

extern "C" void kernel_launch(void* const* d_in, const int* in_sizes, int n_in,
                              void* d_out, int out_size, void* d_ws, size_t ws_size,
                              hipStream_t stream) {
  (void)in_sizes; (void)n_in; (void)out_size; (void)ws_size;
  const float* x = (const float*)d_in[0];      // [2,2048,1024] f32
  const float* wqkv = (const float*)d_in[1];   // [3072,1024]  f32
  const float* wout = (const float*)d_in[2];   // [1024,1024]  f32
  float* out = (float*)d_out;                  // [2,2048,1024] f32

  const size_t elems = (size_t)Bn * Hn * Tn * Dn;  // 4M elems (8 MiB fp16)
  unsigned short* Qf = (unsigned short*)d_ws;
  unsigned short* Kf = Qf + elems;
  unsigned short* Vf = Kf + elems;
  unsigned short* AOf = Vf + elems;
  unsigned short* wf = AOf + elems;                // fp16 w_qkv, 3M
  unsigned short* wof = wf + (size_t)3 * En * En;  // fp16 wout, 1M (40 MiB)

  // d_out (16 MiB) doubles as scratch for x hi/lo; overwritten by gemm_out.
  unsigned short* xh = (unsigned short*)d_out;
  unsigned short* xl = xh + elems;

  const int M = Bn * Tn;  // 4096
  dim3 blk(256);
  split_f32_f16<<<dim3((int)(elems / 1024)), blk, 0, stream>>>(x, xh, xl);
  cvt_f32_f16<<<dim3(3 * En * En / 1024), blk, 0, stream>>>(wqkv, wf);
  cvt_f32_f16<<<dim3(En * En / 1024), blk, 0, stream>>>(wout, wof);
  gemm_qkv<<<dim3(24, M / 128), blk, 0, stream>>>(
      xh, xl, wf, Qf, Kf, Vf, M, En);
  attn_kernel<<<dim3(Tn / 64, Bn * Hn), blk, 0, stream>>>(Qf, Kf, Vf, AOf);
  gemm_out<<<dim3(En / 128, M / 128), blk, 0, stream>>>(
      AOf, wof, out, M, En, En);
}